// Round 5
// baseline (411.764 us; speedup 1.0000x reference)
//
#include <hip/hip_runtime.h>
#include <hip/hip_bf16.h>

#define DIMN 1024
#define NHEAD 8
#define ESPL 128
#define NB 4
#define SEQ 2048
#define NROWS (NB * SEQ)
#define LNEPS 1e-6f

typedef unsigned short u16;
typedef unsigned int u32;
typedef __attribute__((ext_vector_type(8))) short short8;
typedef __attribute__((ext_vector_type(4))) short s16x4;
typedef __attribute__((ext_vector_type(4))) float f32x4;

__device__ __forceinline__ u16 f2bf(float f) {
  u32 u = __float_as_uint(f);
  u += 0x7FFFu + ((u >> 16) & 1u);  // round-to-nearest-even
  return (u16)(u >> 16);
}

__device__ __forceinline__ uint2 pack4bf(float4 v) {
  uint2 r;
  r.x = (u32)f2bf(v.x) | ((u32)f2bf(v.y) << 16);
  r.y = (u32)f2bf(v.z) | ((u32)f2bf(v.w) << 16);
  return r;
}

__device__ __forceinline__ u32 pk2bf(float a, float b) {
  return (u32)f2bf(a) | ((u32)f2bf(b) << 16);
}

__device__ __forceinline__ float eluf(float x) { return x > 0.f ? x : expm1f(x); }

// 256-thread block sum (4 waves). rb is shared float[8].
__device__ __forceinline__ float block_sum256(float v, float* rb, int t) {
#pragma unroll
  for (int o = 32; o > 0; o >>= 1) v += __shfl_down(v, o);
  __syncthreads();
  if ((t & 63) == 0) rb[t >> 6] = v;
  __syncthreads();
  return rb[0] + rb[1] + rb[2] + rb[3];
}

__device__ __forceinline__ float redsum16(float v) {
  v += __shfl_xor(v, 1);
  v += __shfl_xor(v, 2);
  v += __shfl_xor(v, 4);
  v += __shfl_xor(v, 8);
  return v;
}

// ------- weight transpose + fp32->bf16: dst[n*K+k] = bf16(src[k*N+n]) -------
__device__ __forceinline__ void wtrans_body(const float* __restrict__ src,
                                            u16* __restrict__ dst, int K, int N, int n0,
                                            int k0) {
  __shared__ u16 tl[64][68];
  const int t = threadIdx.x;
  const int r = t >> 2;
#pragma unroll
  for (int j = 0; j < 4; j++) {
    int f = (t & 3) + j * 4;
    float4 v = *(const float4*)(src + (size_t)(k0 + r) * N + n0 + f * 4);
    *(uint2*)&tl[r][f * 4] = pack4bf(v);
  }
  __syncthreads();
#pragma unroll
  for (int j = 0; j < 4; j++) {
    int f = (t & 3) + j * 4;
    ushort4 o;
    o.x = tl[f * 4 + 0][r];
    o.y = tl[f * 4 + 1][r];
    o.z = tl[f * 4 + 2][r];
    o.w = tl[f * 4 + 3][r];
    *(ushort4*)(dst + (size_t)(n0 + r) * K + k0 + f * 4) = o;
  }
}

__global__ __launch_bounds__(256) void wtrans_big(const float* __restrict__ sA,
                                                  u16* __restrict__ dA,
                                                  const float* __restrict__ sB,
                                                  u16* __restrict__ dB) {
  const float* s = blockIdx.z ? sB : sA;
  u16* d = blockIdx.z ? dB : dA;
  wtrans_body(s, d, DIMN, DIMN, blockIdx.x * 64, blockIdx.y * 64);
}

__global__ __launch_bounds__(256) void wtrans_small(
    const float* __restrict__ sq, const float* __restrict__ sk, const float* __restrict__ sv,
    u16* __restrict__ dq, u16* __restrict__ dk, u16* __restrict__ dv) {
  const int mi = blockIdx.z >> 3, hh = blockIdx.z & 7;
  const float* s = (mi == 0) ? sq : (mi == 1) ? sk : sv;
  u16* d = (mi == 0) ? dq : (mi == 1) ? dk : dv;
  s += (size_t)hh * ESPL * ESPL;
  d += (size_t)hh * ESPL * ESPL;
  wtrans_body(s, d, ESPL, ESPL, blockIdx.x * 64, blockIdx.y * 64);
}

// ------- bf16 MFMA GEMM, 128x128 tile, BK=64, K=1024 -------
#define GP 72

template <int MODE>
__global__ __launch_bounds__(256) void gemm_mfma(
    const float* __restrict__ A, const u16* __restrict__ Bt, const float* __restrict__ resid,
    const float* __restrict__ bias, const float* __restrict__ gamma,
    const float* __restrict__ beta, float* __restrict__ s1p, float* __restrict__ s2p,
    float* __restrict__ C) {
  __shared__ u16 Asl[128 * GP];
  __shared__ u16 Bsl[128 * GP];
  const int t = threadIdx.x;
  const int w = t >> 6, lane = t & 63, quad = lane >> 4, l16 = lane & 15;
  const int wm = w & 1, wn = w >> 1;
  const int m0 = blockIdx.y * 128, n0 = blockIdx.x * 128;
  const int sr8 = t >> 3, sf8 = t & 7;
  float mu[4], rsd[4];
  if (MODE == 1) {
#pragma unroll
    for (int p = 0; p < 4; p++) {
      int row = m0 + sr8 + 32 * p;
      float s1 = s1p[row], s2 = s2p[row];
      mu[p] = s1 * (1.f / DIMN);
      rsd[p] = rsqrtf(fmaxf(s2 * (1.f / DIMN) - mu[p] * mu[p], 0.f) + LNEPS);
    }
  }
  f32x4 acc[4][4];
#pragma unroll
  for (int mt = 0; mt < 4; mt++)
#pragma unroll
    for (int nt = 0; nt < 4; nt++) acc[mt][nt] = (f32x4){0.f, 0.f, 0.f, 0.f};

  for (int kt = 0; kt < DIMN; kt += 64) {
    __syncthreads();
#pragma unroll
    for (int p = 0; p < 4; p++) {
      int r = sr8 + 32 * p;
      const float* ap = A + (size_t)(m0 + r) * DIMN + kt;
#pragma unroll
      for (int j = 0; j < 2; j++) {
        int f = sf8 + j * 8;
        float4 v = *(const float4*)(ap + f * 4);
        if (MODE == 1) {
          float4 g = *(const float4*)(gamma + kt + f * 4);
          float4 bb = *(const float4*)(beta + kt + f * 4);
          v.x = (v.x - mu[p]) * rsd[p] * g.x + bb.x;
          v.y = (v.y - mu[p]) * rsd[p] * g.y + bb.y;
          v.z = (v.z - mu[p]) * rsd[p] * g.z + bb.z;
          v.w = (v.w - mu[p]) * rsd[p] * g.w + bb.w;
        }
        *(uint2*)(Asl + r * GP + f * 4) = pack4bf(v);
      }
    }
#pragma unroll
    for (int p = 0; p < 4; p++) {
      int r = sr8 + 32 * p;
      *(uint4*)(Bsl + r * GP + sf8 * 8) = *(const uint4*)(Bt + (size_t)(n0 + r) * DIMN + kt + sf8 * 8);
    }
    __syncthreads();
#pragma unroll
    for (int ks = 0; ks < 64; ks += 32) {
      short8 af[4], bfr[4];
#pragma unroll
      for (int mt = 0; mt < 4; mt++)
        af[mt] = *(const short8*)(Asl + (wm * 64 + mt * 16 + l16) * GP + ks + quad * 8);
#pragma unroll
      for (int nt = 0; nt < 4; nt++)
        bfr[nt] = *(const short8*)(Bsl + (wn * 64 + nt * 16 + l16) * GP + ks + quad * 8);
#pragma unroll
      for (int mt = 0; mt < 4; mt++)
#pragma unroll
        for (int nt = 0; nt < 4; nt++)
          acc[mt][nt] = __builtin_amdgcn_mfma_f32_16x16x32_bf16(af[mt], bfr[nt], acc[mt][nt], 0, 0, 0);
    }
  }
#pragma unroll
  for (int mt = 0; mt < 4; mt++) {
#pragma unroll
    for (int r = 0; r < 4; r++) {
      int row = m0 + wm * 64 + mt * 16 + quad * 4 + r;
      float s1 = 0.f, s2 = 0.f;
#pragma unroll
      for (int nt = 0; nt < 4; nt++) {
        int col = n0 + wn * 64 + nt * 16 + l16;
        size_t off = (size_t)row * DIMN + col;
        float v = acc[mt][nt][r];
        if (MODE == 0) {
          C[off] = v;
          s1 += v;
          s2 += v * v;
        } else {
          C[off] = resid[off] + eluf(v + bias[col]);
        }
      }
      if (MODE == 0) {
        s1 = redsum16(s1);
        s2 = redsum16(s2);
        if (l16 == 0) {
          atomicAdd(s1p + row, s1);
          atomicAdd(s2p + row, s2);
        }
      }
    }
  }
}

// ------- QKV: per (b,h), 128 s-rows x 128 e, K=128; LN1 fused in A-staging -------
#define QP 136

__global__ __launch_bounds__(256) void qkv_mfma(
    const float* __restrict__ modp, const u16* __restrict__ wqt, const u16* __restrict__ wkt,
    const u16* __restrict__ wvt, const float* __restrict__ gamma, const float* __restrict__ beta,
    const float* __restrict__ s1p, const float* __restrict__ s2p, u16* __restrict__ qo,
    u16* __restrict__ ko, u16* __restrict__ vto) {
  __shared__ u16 Asl[128 * QP];
  __shared__ u16 Bsl[128 * QP];
  const int t = threadIdx.x;
  const int w = t >> 6, lane = t & 63, quad = lane >> 4, l16 = lane & 15;
  const int wm = w & 1, wn = w >> 1;
  const int s0 = blockIdx.x * 128;
  const int bh = blockIdx.y;
  const int b = bh >> 3, hh = bh & 7;
  const int sr8 = t >> 3, sf8 = t & 7;
#pragma unroll
  for (int p = 0; p < 4; p++) {
    int r = sr8 + 32 * p;
    int rowg = b * SEQ + s0 + r;
    float s1 = s1p[rowg], s2 = s2p[rowg];
    float mu = s1 * (1.f / DIMN);
    float rsd = rsqrtf(fmaxf(s2 * (1.f / DIMN) - mu * mu, 0.f) + LNEPS);
    const float* ap = modp + (size_t)rowg * DIMN + hh * ESPL;
#pragma unroll
    for (int j = 0; j < 4; j++) {
      int f = sf8 + j * 8;
      float4 v = *(const float4*)(ap + f * 4);
      float4 g = *(const float4*)(gamma + hh * ESPL + f * 4);
      float4 bb = *(const float4*)(beta + hh * ESPL + f * 4);
      v.x = (v.x - mu) * rsd * g.x + bb.x;
      v.y = (v.y - mu) * rsd * g.y + bb.y;
      v.z = (v.z - mu) * rsd * g.z + bb.z;
      v.w = (v.w - mu) * rsd * g.w + bb.w;
      *(uint2*)(Asl + r * QP + f * 4) = pack4bf(v);
    }
  }
  __syncthreads();
  short8 afr[4][4];
#pragma unroll
  for (int k4 = 0; k4 < 4; k4++)
#pragma unroll
    for (int mt = 0; mt < 4; mt++)
      afr[k4][mt] = *(const short8*)(Asl + (wm * 64 + mt * 16 + l16) * QP + k4 * 32 + quad * 8);

  const u16* Ws[3] = {wqt, wkt, wvt};
  for (int mi = 0; mi < 3; mi++) {
    __syncthreads();
    const u16* wsrc = Ws[mi] + ((size_t)hh << 14);
#pragma unroll
    for (int p = 0; p < 4; p++) {
      int r = sr8 + 32 * p;
#pragma unroll
      for (int j = 0; j < 2; j++) {
        int f = sf8 + j * 8;
        *(uint4*)(Bsl + r * QP + f * 8) = *(const uint4*)(wsrc + r * ESPL + f * 8);
      }
    }
    __syncthreads();
    f32x4 acc[4][4];
#pragma unroll
    for (int mt = 0; mt < 4; mt++)
#pragma unroll
      for (int nt = 0; nt < 4; nt++) acc[mt][nt] = (f32x4){0.f, 0.f, 0.f, 0.f};
#pragma unroll
    for (int k4 = 0; k4 < 4; k4++) {
      short8 bfr[4];
#pragma unroll
      for (int nt = 0; nt < 4; nt++)
        bfr[nt] = *(const short8*)(Bsl + (wn * 64 + nt * 16 + l16) * QP + k4 * 32 + quad * 8);
#pragma unroll
      for (int mt = 0; mt < 4; mt++)
#pragma unroll
        for (int nt = 0; nt < 4; nt++)
          acc[mt][nt] = __builtin_amdgcn_mfma_f32_16x16x32_bf16(afr[k4][mt], bfr[nt], acc[mt][nt], 0, 0, 0);
    }
    if (mi < 2) {
      u16* o = (mi == 0) ? qo : ko;
#pragma unroll
      for (int mt = 0; mt < 4; mt++)
#pragma unroll
        for (int r = 0; r < 4; r++) {
          int s = s0 + wm * 64 + mt * 16 + quad * 4 + r;
#pragma unroll
          for (int nt = 0; nt < 4; nt++) {
            int e = wn * 64 + nt * 16 + l16;
            o[((size_t)bh * SEQ + s) * ESPL + e] = f2bf(acc[mt][nt][r]);
          }
        }
    } else {
#pragma unroll
      for (int mt = 0; mt < 4; mt++)
#pragma unroll
        for (int nt = 0; nt < 4; nt++) {
          int e = wn * 64 + nt * 16 + l16;
          int sbase = s0 + wm * 64 + mt * 16 + quad * 4;
          ushort4 pk;
          pk.x = f2bf(acc[mt][nt][0]);
          pk.y = f2bf(acc[mt][nt][1]);
          pk.z = f2bf(acc[mt][nt][2]);
          pk.w = f2bf(acc[mt][nt][3]);
          *(ushort4*)(vto + ((size_t)bh * ESPL + e) * SEQ + sbase) = pk;
        }
    }
  }
}

// ------- MFMA flash attention v3: S^T formulation, register prefetch -------
// S^T = K·Q^T (C-layout of S^T == B-frag layout of 16x16x16 MFMA for P^T)
// O^T = V^T·P^T. No P transpose through LDS. K/V tiles prefetched to regs.
#define KP 136  // Ks pitch (u16): 64 kv x 128 e
#define VP 72   // Vs pitch (u16): 128 e x 64 kv
#define OBP 132 // epilogue Obuf pitch (f32): 32 q x 128 e

__global__ __launch_bounds__(256, 2) void attn_mfma(const u16* __restrict__ q,
                                                    const u16* __restrict__ kk,
                                                    const u16* __restrict__ vt,
                                                    float* __restrict__ modp,
                                                    float* __restrict__ s1p,
                                                    float* __restrict__ s2p) {
  __shared__ __align__(16) char lds[64 * KP * 2 + 128 * VP * 2];  // 35840 B
  u16* Ks = (u16*)lds;
  u16* Vs = (u16*)(lds + 64 * KP * 2);
  float* Obuf = (float*)lds;  // epilogue reuse
  const int t = threadIdx.x;
  const int w = t >> 6, lane = t & 63, quad = lane >> 4, l16 = lane & 15;
  const int qt = blockIdx.x;  // 0..15
  const int bh = blockIdx.y;  // 0..31
  const int b = bh >> 3, hh = bh & 7;
  const size_t qkbase = (size_t)bh * SEQ * ESPL;
  const int qrow0 = qt * 128 + w * 32;

  // Q B-frags (registers, persistent): 2 groups x 4 k-chunks
  short8 qf[2][4];
#pragma unroll
  for (int g = 0; g < 2; g++) {
    const u16* qrow = q + qkbase + (size_t)(qrow0 + g * 16 + l16) * ESPL + quad * 8;
#pragma unroll
    for (int kc = 0; kc < 4; kc++) qf[g][kc] = *(const short8*)(qrow + kc * 32);
  }

  float m_st[2] = {-1e30f, -1e30f}, l_st[2] = {0.f, 0.f};
  f32x4 oacc[2][8];
#pragma unroll
  for (int g = 0; g < 2; g++)
#pragma unroll
    for (int et = 0; et < 8; et++) oacc[g][et] = (f32x4){0.f, 0.f, 0.f, 0.f};

  // stage tile 0
  {
    const u16* kg = kk + qkbase;
    const u16* vg = vt + qkbase;
#pragma unroll
    for (int p = 0; p < 4; p++) {
      int idx = t + (p << 8);
      int r = idx >> 4, c = (idx & 15) << 3;
      *(uint4*)(Ks + r * KP + c) = *(const uint4*)(kg + r * ESPL + c);
    }
#pragma unroll
    for (int p = 0; p < 4; p++) {
      int idx = t + (p << 8);
      int e = idx >> 3, c = (idx & 7) << 3;
      *(uint4*)(Vs + e * VP + c) = *(const uint4*)(vg + (size_t)e * SEQ + c);
    }
  }
  __syncthreads();

  for (int kt = 0; kt < SEQ / 64; kt++) {
    // prefetch next tile into registers (overlaps with compute below)
    uint4 kr[4], vr[4];
    const bool havenext = (kt + 1) < SEQ / 64;
    if (havenext) {
      const u16* kg = kk + qkbase + (size_t)(kt + 1) * 64 * ESPL;
      const u16* vg = vt + qkbase + (size_t)(kt + 1) * 64;
#pragma unroll
      for (int p = 0; p < 4; p++) {
        int idx = t + (p << 8);
        kr[p] = *(const uint4*)(kg + (size_t)(idx >> 4) * ESPL + ((idx & 15) << 3));
        vr[p] = *(const uint4*)(vg + (size_t)(idx >> 3) * SEQ + ((idx & 7) << 3));
      }
    }
    // QK^T -> S^T: A = K (LDS), B = Q^T (regs). S^T[kv][q]
    f32x4 sacc[4][2];
#pragma unroll
    for (int mt = 0; mt < 4; mt++)
#pragma unroll
      for (int g = 0; g < 2; g++) sacc[mt][g] = (f32x4){0.f, 0.f, 0.f, 0.f};
#pragma unroll
    for (int mt = 0; mt < 4; mt++) {
#pragma unroll
      for (int kc = 0; kc < 4; kc++) {
        short8 kf = *(const short8*)(Ks + (mt * 16 + l16) * KP + kc * 32 + quad * 8);
        sacc[mt][0] = __builtin_amdgcn_mfma_f32_16x16x32_bf16(kf, qf[0][kc], sacc[mt][0], 0, 0, 0);
        sacc[mt][1] = __builtin_amdgcn_mfma_f32_16x16x32_bf16(kf, qf[1][kc], sacc[mt][1], 0, 0, 0);
      }
    }
    // register online softmax (per column q = g*16+l16); build P^T B-frags in regs
    s16x4 pfrag[2][4];
    float alpha[2];
#pragma unroll
    for (int g = 0; g < 2; g++) {
      float mloc = sacc[0][g][0];
#pragma unroll
      for (int mt = 0; mt < 4; mt++)
#pragma unroll
        for (int r = 0; r < 4; r++) mloc = fmaxf(mloc, sacc[mt][g][r]);
      mloc = fmaxf(mloc, __shfl_xor(mloc, 16));
      mloc = fmaxf(mloc, __shfl_xor(mloc, 32));
      float mnew = fmaxf(m_st[g], mloc);
      alpha[g] = __expf(m_st[g] - mnew);
      m_st[g] = mnew;
      float sum = 0.f;
#pragma unroll
      for (int mt = 0; mt < 4; mt++) {
        float p0 = __expf(sacc[mt][g][0] - mnew);
        float p1 = __expf(sacc[mt][g][1] - mnew);
        float p2 = __expf(sacc[mt][g][2] - mnew);
        float p3 = __expf(sacc[mt][g][3] - mnew);
        sum += (p0 + p1) + (p2 + p3);
        union {
          s16x4 s;
          uint2 u;
        } cv;
        cv.u = make_uint2(pk2bf(p0, p1), pk2bf(p2, p3));
        pfrag[g][mt] = cv.s;
      }
      sum += __shfl_xor(sum, 16);
      sum += __shfl_xor(sum, 32);
      l_st[g] = l_st[g] * alpha[g] + sum;
    }
    // rescale O^T accumulators
#pragma unroll
    for (int g = 0; g < 2; g++)
#pragma unroll
      for (int et = 0; et < 8; et++)
#pragma unroll
        for (int r = 0; r < 4; r++) oacc[g][et][r] *= alpha[g];
    // PV: O^T += V^T · P^T  (A = V^T from LDS, B = P^T regs, K=16 MFMA)
#pragma unroll
    for (int et = 0; et < 8; et++) {
#pragma unroll
      for (int mt = 0; mt < 4; mt++) {
        s16x4 vf = *(const s16x4*)(Vs + (et * 16 + l16) * VP + mt * 16 + quad * 4);
        oacc[0][et] = __builtin_amdgcn_mfma_f32_16x16x16bf16_1k(vf, pfrag[0][mt], oacc[0][et], 0, 0, 0);
        oacc[1][et] = __builtin_amdgcn_mfma_f32_16x16x16bf16_1k(vf, pfrag[1][mt], oacc[1][et], 0, 0, 0);
      }
    }
    __syncthreads();  // all waves done reading Ks/Vs
    if (havenext) {
#pragma unroll
      for (int p = 0; p < 4; p++) {
        int idx = t + (p << 8);
        *(uint4*)(Ks + (idx >> 4) * KP + ((idx & 15) << 3)) = kr[p];
        *(uint4*)(Vs + (idx >> 3) * VP + ((idx & 7) << 3)) = vr[p];
      }
    }
    __syncthreads();  // staging visible
  }

  // epilogue: per 32-q chunk, transpose O^T through LDS, coalesced RMW + stats
  const int rr = t >> 3, cc = (t & 7) << 4;
  for (int c = 0; c < 4; c++) {
    if (w == c) {
      float linv[2] = {1.f / l_st[0], 1.f / l_st[1]};
#pragma unroll
      for (int g = 0; g < 2; g++)
#pragma unroll
        for (int et = 0; et < 8; et++) {
          f32x4 ov = oacc[g][et];
          ov[0] *= linv[g];
          ov[1] *= linv[g];
          ov[2] *= linv[g];
          ov[3] *= linv[g];
          *(f32x4*)(Obuf + (size_t)(g * 16 + l16) * OBP + et * 16 + quad * 4) = ov;
        }
    }
    __syncthreads();
    int qglob = qt * 128 + c * 32 + rr;
    float* mp = modp + ((size_t)(b * SEQ + qglob)) * DIMN + hh * ESPL + cc;
    float s1 = 0.f, s2 = 0.f;
#pragma unroll
    for (int j = 0; j < 4; j++) {
      float4 ov = *(const float4*)(Obuf + (size_t)rr * OBP + cc + j * 4);
      float4 mv = *(const float4*)(mp + j * 4);
      mv.x += ov.x;
      mv.y += ov.y;
      mv.z += ov.z;
      mv.w += ov.w;
      *(float4*)(mp + j * 4) = mv;
      s1 += (mv.x + mv.y) + (mv.z + mv.w);
      s2 += (mv.x * mv.x + mv.y * mv.y) + (mv.z * mv.z + mv.w * mv.w);
    }
    s1 += __shfl_xor(s1, 1);
    s1 += __shfl_xor(s1, 2);
    s1 += __shfl_xor(s1, 4);
    s2 += __shfl_xor(s2, 1);
    s2 += __shfl_xor(s2, 2);
    s2 += __shfl_xor(s2, 4);
    if ((t & 7) == 0) {
      atomicAdd(s1p + b * SEQ + qglob, s1);
      atomicAdd(s2p + b * SEQ + qglob, s2);
    }
    __syncthreads();
  }
}

extern "C" void kernel_launch(void* const* d_in, const int* in_sizes, int n_in, void* d_out,
                              int out_size, void* d_ws, size_t ws_size, hipStream_t stream) {
  (void)in_sizes;
  (void)n_in;
  (void)out_size;
  (void)ws_size;
  const float* x = (const float*)d_in[0];
  const float* W_in = (const float*)d_in[1];
  const float* gamma = (const float*)d_in[2];
  const float* beta = (const float*)d_in[3];
  const float* Wq = (const float*)d_in[4];
  const float* Wk = (const float*)d_in[5];
  const float* Wv = (const float*)d_in[6];
  const float* Wf = (const float*)d_in[7];
  const float* bf = (const float*)d_in[8];
  float* out = (float*)d_out;

  char* ws = (char*)d_ws;
  const size_t MB = 1024ull * 1024;
  float* mod = (float*)ws;                 // 32 MB fp32 [8192,1024]
  u16* qb = (u16*)(ws + 32 * MB);          // 16 MB bf16 [B,H,S,E]
  u16* kb = (u16*)(ws + 48 * MB);          // 16 MB bf16 [B,H,S,E]
  u16* vtb = (u16*)(ws + 64 * MB);         // 16 MB bf16 [B,H,E,S]
  float* sums = (float*)(ws + 80 * MB);    // 4 x 32 KB: s1a,s2a,s1b,s2b
  float* s1a = sums;
  float* s2a = s1a + NROWS;
  float* s1b = s2a + NROWS;
  float* s2b = s1b + NROWS;
  u16* wqt = (u16*)(ws + 80 * MB + 4 * NROWS * sizeof(float));
  u16* wkt = wqt + NHEAD * ESPL * ESPL;
  u16* wvt = wkt + NHEAD * ESPL * ESPL;
  u16* wt2 = wvt + NHEAD * ESPL * ESPL;  // 2 MB Wf^T bf16
  u16* wt1 = (u16*)(ws + 32 * MB);       // W_in^T bf16 overlaps qb (dead before qkv writes qb)

  hipMemsetAsync(sums, 0, 4 * NROWS * sizeof(float), stream);
  wtrans_big<<<dim3(16, 16, 2), 256, 0, stream>>>(W_in, wt1, Wf, wt2);
  wtrans_small<<<dim3(2, 2, 24), 256, 0, stream>>>(Wq, Wk, Wv, wqt, wkt, wvt);

  dim3 gg(DIMN / 128, NROWS / 128);  // (8, 64)
  gemm_mfma<0><<<gg, 256, 0, stream>>>(x, wt1, nullptr, nullptr, nullptr, nullptr, s1a, s2a, mod);
  qkv_mfma<<<dim3(SEQ / 128, NB * NHEAD), 256, 0, stream>>>(mod, wqt, wkt, wvt, gamma, beta,
                                                            s1a, s2a, qb, kb, vtb);
  attn_mfma<<<dim3(SEQ / 128, NB * NHEAD), 256, 0, stream>>>(qb, kb, vtb, mod, s1b, s2b);
  gemm_mfma<1><<<gg, 256, 0, stream>>>(mod, wt2, mod, bf, gamma, beta, s1b, s2b, out);
}

// Round 6
// 341.249 us; speedup vs baseline: 1.2066x; 1.2066x over previous
//
#include <hip/hip_runtime.h>
#include <hip/hip_bf16.h>

#define DIMN 1024
#define NHEAD 8
#define ESPL 128
#define NB 4
#define SEQ 2048
#define NROWS (NB * SEQ)
#define LNEPS 1e-6f

typedef unsigned short u16;
typedef unsigned int u32;
typedef __attribute__((ext_vector_type(8))) short short8;
typedef __attribute__((ext_vector_type(4))) short s16x4;
typedef __attribute__((ext_vector_type(4))) float f32x4;

__device__ __forceinline__ u16 f2bf(float f) {
  u32 u = __float_as_uint(f);
  u += 0x7FFFu + ((u >> 16) & 1u);  // round-to-nearest-even
  return (u16)(u >> 16);
}

__device__ __forceinline__ uint2 pack4bf(float4 v) {
  uint2 r;
  r.x = (u32)f2bf(v.x) | ((u32)f2bf(v.y) << 16);
  r.y = (u32)f2bf(v.z) | ((u32)f2bf(v.w) << 16);
  return r;
}

__device__ __forceinline__ u32 pk2bf(float a, float b) {
  return (u32)f2bf(a) | ((u32)f2bf(b) << 16);
}

__device__ __forceinline__ float eluf(float x) { return x > 0.f ? x : expm1f(x); }

__device__ __forceinline__ float redsum16(float v) {
  v += __shfl_xor(v, 1);
  v += __shfl_xor(v, 2);
  v += __shfl_xor(v, 4);
  v += __shfl_xor(v, 8);
  return v;
}

// async global->LDS DMA, 16 B per lane; lds dest = wave-uniform base + lane*16
__device__ __forceinline__ void gl2lds16(const u16* g, u16* l) {
  __builtin_amdgcn_global_load_lds((const __attribute__((address_space(1))) u32*)g,
                                   (__attribute__((address_space(3))) u32*)l, 16, 0, 0);
}

// ------- weight transpose + fp32->bf16: dst[n*K+k] = bf16(src[k*N+n]) -------
__device__ __forceinline__ void wtrans_body(const float* __restrict__ src,
                                            u16* __restrict__ dst, int K, int N, int n0,
                                            int k0) {
  __shared__ u16 tl[64][68];
  const int t = threadIdx.x;
  const int r = t >> 2;
#pragma unroll
  for (int j = 0; j < 4; j++) {
    int f = (t & 3) + j * 4;
    float4 v = *(const float4*)(src + (size_t)(k0 + r) * N + n0 + f * 4);
    *(uint2*)&tl[r][f * 4] = pack4bf(v);
  }
  __syncthreads();
#pragma unroll
  for (int j = 0; j < 4; j++) {
    int f = (t & 3) + j * 4;
    ushort4 o;
    o.x = tl[f * 4 + 0][r];
    o.y = tl[f * 4 + 1][r];
    o.z = tl[f * 4 + 2][r];
    o.w = tl[f * 4 + 3][r];
    *(ushort4*)(dst + (size_t)(n0 + r) * K + k0 + f * 4) = o;
  }
}

__global__ __launch_bounds__(256) void wtrans_big(const float* __restrict__ sA,
                                                  u16* __restrict__ dA,
                                                  const float* __restrict__ sB,
                                                  u16* __restrict__ dB) {
  const float* s = blockIdx.z ? sB : sA;
  u16* d = blockIdx.z ? dB : dA;
  wtrans_body(s, d, DIMN, DIMN, blockIdx.x * 64, blockIdx.y * 64);
}

__global__ __launch_bounds__(256) void wtrans_small(
    const float* __restrict__ sq, const float* __restrict__ sk, const float* __restrict__ sv,
    u16* __restrict__ dq, u16* __restrict__ dk, u16* __restrict__ dv) {
  const int mi = blockIdx.z >> 3, hh = blockIdx.z & 7;
  const float* s = (mi == 0) ? sq : (mi == 1) ? sk : sv;
  u16* d = (mi == 0) ? dq : (mi == 1) ? dk : dv;
  s += (size_t)hh * ESPL * ESPL;
  d += (size_t)hh * ESPL * ESPL;
  wtrans_body(s, d, ESPL, ESPL, blockIdx.x * 64, blockIdx.y * 64);
}

// ------- bf16 MFMA GEMM, 128x128 tile, BK=64, K=1024 -------
#define GP 72

template <int MODE>
__global__ __launch_bounds__(256) void gemm_mfma(
    const float* __restrict__ A, const u16* __restrict__ Bt, const float* __restrict__ resid,
    const float* __restrict__ bias, const float* __restrict__ gamma,
    const float* __restrict__ beta, float* __restrict__ s1p, float* __restrict__ s2p,
    float* __restrict__ C) {
  __shared__ u16 Asl[128 * GP];
  __shared__ u16 Bsl[128 * GP];
  const int t = threadIdx.x;
  const int w = t >> 6, lane = t & 63, quad = lane >> 4, l16 = lane & 15;
  const int wm = w & 1, wn = w >> 1;
  const int m0 = blockIdx.y * 128, n0 = blockIdx.x * 128;
  const int sr8 = t >> 3, sf8 = t & 7;
  float mu[4], rsd[4];
  if (MODE == 1) {
#pragma unroll
    for (int p = 0; p < 4; p++) {
      int row = m0 + sr8 + 32 * p;
      float s1 = s1p[row], s2 = s2p[row];
      mu[p] = s1 * (1.f / DIMN);
      rsd[p] = rsqrtf(fmaxf(s2 * (1.f / DIMN) - mu[p] * mu[p], 0.f) + LNEPS);
    }
  }
  f32x4 acc[4][4];
#pragma unroll
  for (int mt = 0; mt < 4; mt++)
#pragma unroll
    for (int nt = 0; nt < 4; nt++) acc[mt][nt] = (f32x4){0.f, 0.f, 0.f, 0.f};

  for (int kt = 0; kt < DIMN; kt += 64) {
    __syncthreads();
#pragma unroll
    for (int p = 0; p < 4; p++) {
      int r = sr8 + 32 * p;
      const float* ap = A + (size_t)(m0 + r) * DIMN + kt;
#pragma unroll
      for (int j = 0; j < 2; j++) {
        int f = sf8 + j * 8;
        float4 v = *(const float4*)(ap + f * 4);
        if (MODE == 1) {
          float4 g = *(const float4*)(gamma + kt + f * 4);
          float4 bb = *(const float4*)(beta + kt + f * 4);
          v.x = (v.x - mu[p]) * rsd[p] * g.x + bb.x;
          v.y = (v.y - mu[p]) * rsd[p] * g.y + bb.y;
          v.z = (v.z - mu[p]) * rsd[p] * g.z + bb.z;
          v.w = (v.w - mu[p]) * rsd[p] * g.w + bb.w;
        }
        *(uint2*)(Asl + r * GP + f * 4) = pack4bf(v);
      }
    }
#pragma unroll
    for (int p = 0; p < 4; p++) {
      int r = sr8 + 32 * p;
      *(uint4*)(Bsl + r * GP + sf8 * 8) = *(const uint4*)(Bt + (size_t)(n0 + r) * DIMN + kt + sf8 * 8);
    }
    __syncthreads();
#pragma unroll
    for (int ks = 0; ks < 64; ks += 32) {
      short8 af[4], bfr[4];
#pragma unroll
      for (int mt = 0; mt < 4; mt++)
        af[mt] = *(const short8*)(Asl + (wm * 64 + mt * 16 + l16) * GP + ks + quad * 8);
#pragma unroll
      for (int nt = 0; nt < 4; nt++)
        bfr[nt] = *(const short8*)(Bsl + (wn * 64 + nt * 16 + l16) * GP + ks + quad * 8);
#pragma unroll
      for (int mt = 0; mt < 4; mt++)
#pragma unroll
        for (int nt = 0; nt < 4; nt++)
          acc[mt][nt] = __builtin_amdgcn_mfma_f32_16x16x32_bf16(af[mt], bfr[nt], acc[mt][nt], 0, 0, 0);
    }
  }
#pragma unroll
  for (int mt = 0; mt < 4; mt++) {
#pragma unroll
    for (int r = 0; r < 4; r++) {
      int row = m0 + wm * 64 + mt * 16 + quad * 4 + r;
      float s1 = 0.f, s2 = 0.f;
#pragma unroll
      for (int nt = 0; nt < 4; nt++) {
        int col = n0 + wn * 64 + nt * 16 + l16;
        size_t off = (size_t)row * DIMN + col;
        float v = acc[mt][nt][r];
        if (MODE == 0) {
          C[off] = v;
          s1 += v;
          s2 += v * v;
        } else {
          C[off] = resid[off] + eluf(v + bias[col]);
        }
      }
      if (MODE == 0) {
        s1 = redsum16(s1);
        s2 = redsum16(s2);
        if (l16 == 0) {
          atomicAdd(s1p + row, s1);
          atomicAdd(s2p + row, s2);
        }
      }
    }
  }
}

// ------- QKV: per (b,h), 128 s-rows x 128 e, K=128; LN1 fused in A-staging -------
#define QP 136

__global__ __launch_bounds__(256) void qkv_mfma(
    const float* __restrict__ modp, const u16* __restrict__ wqt, const u16* __restrict__ wkt,
    const u16* __restrict__ wvt, const float* __restrict__ gamma, const float* __restrict__ beta,
    const float* __restrict__ s1p, const float* __restrict__ s2p, u16* __restrict__ qo,
    u16* __restrict__ ko, u16* __restrict__ vto) {
  __shared__ u16 Asl[128 * QP];
  __shared__ u16 Bsl[128 * QP];
  const int t = threadIdx.x;
  const int w = t >> 6, lane = t & 63, quad = lane >> 4, l16 = lane & 15;
  const int wm = w & 1, wn = w >> 1;
  const int s0 = blockIdx.x * 128;
  const int bh = blockIdx.y;
  const int b = bh >> 3, hh = bh & 7;
  const int sr8 = t >> 3, sf8 = t & 7;
#pragma unroll
  for (int p = 0; p < 4; p++) {
    int r = sr8 + 32 * p;
    int rowg = b * SEQ + s0 + r;
    float s1 = s1p[rowg], s2 = s2p[rowg];
    float mu = s1 * (1.f / DIMN);
    float rsd = rsqrtf(fmaxf(s2 * (1.f / DIMN) - mu * mu, 0.f) + LNEPS);
    const float* ap = modp + (size_t)rowg * DIMN + hh * ESPL;
#pragma unroll
    for (int j = 0; j < 4; j++) {
      int f = sf8 + j * 8;
      float4 v = *(const float4*)(ap + f * 4);
      float4 g = *(const float4*)(gamma + hh * ESPL + f * 4);
      float4 bb = *(const float4*)(beta + hh * ESPL + f * 4);
      v.x = (v.x - mu) * rsd * g.x + bb.x;
      v.y = (v.y - mu) * rsd * g.y + bb.y;
      v.z = (v.z - mu) * rsd * g.z + bb.z;
      v.w = (v.w - mu) * rsd * g.w + bb.w;
      *(uint2*)(Asl + r * QP + f * 4) = pack4bf(v);
    }
  }
  __syncthreads();
  short8 afr[4][4];
#pragma unroll
  for (int k4 = 0; k4 < 4; k4++)
#pragma unroll
    for (int mt = 0; mt < 4; mt++)
      afr[k4][mt] = *(const short8*)(Asl + (wm * 64 + mt * 16 + l16) * QP + k4 * 32 + quad * 8);

  const u16* Ws[3] = {wqt, wkt, wvt};
  for (int mi = 0; mi < 3; mi++) {
    __syncthreads();
    const u16* wsrc = Ws[mi] + ((size_t)hh << 14);
#pragma unroll
    for (int p = 0; p < 4; p++) {
      int r = sr8 + 32 * p;
#pragma unroll
      for (int j = 0; j < 2; j++) {
        int f = sf8 + j * 8;
        *(uint4*)(Bsl + r * QP + f * 8) = *(const uint4*)(wsrc + r * ESPL + f * 8);
      }
    }
    __syncthreads();
    f32x4 acc[4][4];
#pragma unroll
    for (int mt = 0; mt < 4; mt++)
#pragma unroll
      for (int nt = 0; nt < 4; nt++) acc[mt][nt] = (f32x4){0.f, 0.f, 0.f, 0.f};
#pragma unroll
    for (int k4 = 0; k4 < 4; k4++) {
      short8 bfr[4];
#pragma unroll
      for (int nt = 0; nt < 4; nt++)
        bfr[nt] = *(const short8*)(Bsl + (wn * 64 + nt * 16 + l16) * QP + k4 * 32 + quad * 8);
#pragma unroll
      for (int mt = 0; mt < 4; mt++)
#pragma unroll
        for (int nt = 0; nt < 4; nt++)
          acc[mt][nt] = __builtin_amdgcn_mfma_f32_16x16x32_bf16(afr[k4][mt], bfr[nt], acc[mt][nt], 0, 0, 0);
    }
    if (mi < 2) {
      u16* o = (mi == 0) ? qo : ko;
#pragma unroll
      for (int mt = 0; mt < 4; mt++)
#pragma unroll
        for (int r = 0; r < 4; r++) {
          int s = s0 + wm * 64 + mt * 16 + quad * 4 + r;
#pragma unroll
          for (int nt = 0; nt < 4; nt++) {
            int e = wn * 64 + nt * 16 + l16;
            o[((size_t)bh * SEQ + s) * ESPL + e] = f2bf(acc[mt][nt][r]);
          }
        }
    } else {
#pragma unroll
      for (int mt = 0; mt < 4; mt++)
#pragma unroll
        for (int nt = 0; nt < 4; nt++) {
          int e = wn * 64 + nt * 16 + l16;
          int sbase = s0 + wm * 64 + mt * 16 + quad * 4;
          ushort4 pk;
          pk.x = f2bf(acc[mt][nt][0]);
          pk.y = f2bf(acc[mt][nt][1]);
          pk.z = f2bf(acc[mt][nt][2]);
          pk.w = f2bf(acc[mt][nt][3]);
          *(ushort4*)(vto + ((size_t)bh * ESPL + e) * SEQ + sbase) = pk;
        }
    }
  }
}

// ------- MFMA flash attention v4: S^T formulation + async LDS double-buffer -------
// S^T = K·Q^T; O^T = V^T·P^T. K/V staged by global_load_lds (no VGPR cost) into
// unpadded XOR-swizzled tiles (swizzle applied on the GLOBAL address so the DMA's
// contiguous lane->LDS mapping yields conflict-light reads).
// K tile: 64 kv x 128 e u16 (16 chunks/row, phys c8 = c8 ^ (kv&15)) = 16 KB
// V tile: 128 e x 64 kv u16  (8 chunks/row, phys c8 = c8 ^ (e&7))  = 16 KB
#define OBP 132  // epilogue Obuf pitch (f32)

__global__ __launch_bounds__(256, 2) void attn_mfma(const u16* __restrict__ q,
                                                    const u16* __restrict__ kk,
                                                    const u16* __restrict__ vt,
                                                    float* __restrict__ modp,
                                                    float* __restrict__ s1p,
                                                    float* __restrict__ s2p) {
  __shared__ __align__(16) char lds[65536];  // [Ks0|Vs0|Ks1|Vs1] 16 KB each
  const int t = threadIdx.x;
  const int w = t >> 6, lane = t & 63, quad = lane >> 4, l16 = lane & 15;
  const int qt = blockIdx.x;  // 0..15
  const int bh = blockIdx.y;  // 0..31
  const int b = bh >> 3, hh = bh & 7;
  const size_t qkbase = (size_t)bh * SEQ * ESPL;
  const int qrow0 = qt * 128 + w * 32;
  const u16* kg0 = kk + qkbase;
  const u16* vg0 = vt + qkbase;

  // Q B-frags (registers, persistent): 2 groups x 4 k-chunks
  short8 qf[2][4];
#pragma unroll
  for (int g = 0; g < 2; g++) {
    const u16* qrow = q + qkbase + (size_t)(qrow0 + g * 16 + l16) * ESPL + quad * 8;
#pragma unroll
    for (int kc = 0; kc < 4; kc++) qf[g][kc] = *(const short8*)(qrow + kc * 32);
  }

  float m_st[2] = {-1e30f, -1e30f}, l_st[2] = {0.f, 0.f};
  f32x4 oacc[2][8];
#pragma unroll
  for (int g = 0; g < 2; g++)
#pragma unroll
    for (int et = 0; et < 8; et++) oacc[g][et] = (f32x4){0.f, 0.f, 0.f, 0.f};

  // async stage one K/V tile into buffer bi
  auto stage = [&](int kt, int bi) {
    const u16* kg = kg0 + (size_t)kt * 64 * ESPL;
    const u16* vg = vg0 + (size_t)kt * 64;
    u16* Ksb = (u16*)(lds + bi * 32768);
    u16* Vsb = (u16*)(lds + bi * 32768 + 16384);
#pragma unroll
    for (int i = 0; i < 4; i++) {
      int pbase = w * 64 + i * 256;
      int p = pbase + lane;
      int r = p >> 4, c8 = (p & 15) ^ (r & 15);
      gl2lds16(kg + r * ESPL + c8 * 8, Ksb + pbase * 8);
      int e = p >> 3, v8 = (p & 7) ^ (e & 7);
      gl2lds16(vg + (size_t)e * SEQ + v8 * 8, Vsb + pbase * 8);
    }
  };

  stage(0, 0);
  __syncthreads();

  for (int kt = 0; kt < SEQ / 64; kt++) {
    if (kt + 1 < SEQ / 64) stage(kt + 1, (kt + 1) & 1);
    const u16* Ks = (const u16*)(lds + (kt & 1) * 32768);
    const u16* Vs = (const u16*)(lds + (kt & 1) * 32768 + 16384);
    // QK^T -> S^T: A = K (LDS, swizzled), B = Q^T (regs). S^T[kv][q]
    f32x4 sacc[4][2];
#pragma unroll
    for (int mt = 0; mt < 4; mt++)
#pragma unroll
      for (int g = 0; g < 2; g++) sacc[mt][g] = (f32x4){0.f, 0.f, 0.f, 0.f};
#pragma unroll
    for (int mt = 0; mt < 4; mt++) {
#pragma unroll
      for (int kc = 0; kc < 4; kc++) {
        short8 kf = *(const short8*)(Ks + (mt * 16 + l16) * 128 + (((kc * 4 + quad) ^ l16) << 3));
        sacc[mt][0] = __builtin_amdgcn_mfma_f32_16x16x32_bf16(kf, qf[0][kc], sacc[mt][0], 0, 0, 0);
        sacc[mt][1] = __builtin_amdgcn_mfma_f32_16x16x32_bf16(kf, qf[1][kc], sacc[mt][1], 0, 0, 0);
      }
    }
    // register online softmax (per column q = g*16+l16); build P^T B-frags in regs
    s16x4 pfrag[2][4];
    float alpha[2];
#pragma unroll
    for (int g = 0; g < 2; g++) {
      float mloc = sacc[0][g][0];
#pragma unroll
      for (int mt = 0; mt < 4; mt++)
#pragma unroll
        for (int r = 0; r < 4; r++) mloc = fmaxf(mloc, sacc[mt][g][r]);
      mloc = fmaxf(mloc, __shfl_xor(mloc, 16));
      mloc = fmaxf(mloc, __shfl_xor(mloc, 32));
      float mnew = fmaxf(m_st[g], mloc);
      alpha[g] = __expf(m_st[g] - mnew);
      m_st[g] = mnew;
      float sum = 0.f;
#pragma unroll
      for (int mt = 0; mt < 4; mt++) {
        float p0 = __expf(sacc[mt][g][0] - mnew);
        float p1 = __expf(sacc[mt][g][1] - mnew);
        float p2 = __expf(sacc[mt][g][2] - mnew);
        float p3 = __expf(sacc[mt][g][3] - mnew);
        sum += (p0 + p1) + (p2 + p3);
        union {
          s16x4 s;
          uint2 u;
        } cv;
        cv.u = make_uint2(pk2bf(p0, p1), pk2bf(p2, p3));
        pfrag[g][mt] = cv.s;
      }
      sum += __shfl_xor(sum, 16);
      sum += __shfl_xor(sum, 32);
      l_st[g] = l_st[g] * alpha[g] + sum;
    }
    // rescale O^T accumulators
#pragma unroll
    for (int g = 0; g < 2; g++)
#pragma unroll
      for (int et = 0; et < 8; et++)
#pragma unroll
        for (int r = 0; r < 4; r++) oacc[g][et][r] *= alpha[g];
    // PV: O^T += V^T · P^T  (A = V^T from LDS swizzled, B = P^T regs, K=16 MFMA)
#pragma unroll
    for (int et = 0; et < 8; et++) {
#pragma unroll
      for (int mt = 0; mt < 4; mt++) {
        s16x4 vf = *(const s16x4*)(Vs + (size_t)(et * 16 + l16) * 64 +
                                   ((((mt * 2 + (quad >> 1)) ^ (l16 & 7)) << 3) + (quad & 1) * 4));
        oacc[0][et] = __builtin_amdgcn_mfma_f32_16x16x16bf16_1k(vf, pfrag[0][mt], oacc[0][et], 0, 0, 0);
        oacc[1][et] = __builtin_amdgcn_mfma_f32_16x16x16bf16_1k(vf, pfrag[1][mt], oacc[1][et], 0, 0, 0);
      }
    }
    __syncthreads();  // drains DMA (vmcnt) + all waves done reading this buffer
  }

  // epilogue: per 32-q chunk, transpose O^T through LDS, coalesced RMW + stats
  float* Obuf = (float*)lds;
  const int rr = t >> 3, cc = (t & 7) << 4;
  for (int c = 0; c < 4; c++) {
    if (w == c) {
      float linv[2] = {1.f / l_st[0], 1.f / l_st[1]};
#pragma unroll
      for (int g = 0; g < 2; g++)
#pragma unroll
        for (int et = 0; et < 8; et++) {
          f32x4 ov = oacc[g][et];
          ov[0] *= linv[g];
          ov[1] *= linv[g];
          ov[2] *= linv[g];
          ov[3] *= linv[g];
          *(f32x4*)(Obuf + (size_t)(g * 16 + l16) * OBP + et * 16 + quad * 4) = ov;
        }
    }
    __syncthreads();
    int qglob = qt * 128 + c * 32 + rr;
    float* mp = modp + ((size_t)(b * SEQ + qglob)) * DIMN + hh * ESPL + cc;
    float s1 = 0.f, s2 = 0.f;
#pragma unroll
    for (int j = 0; j < 4; j++) {
      float4 ov = *(const float4*)(Obuf + (size_t)rr * OBP + cc + j * 4);
      float4 mv = *(const float4*)(mp + j * 4);
      mv.x += ov.x;
      mv.y += ov.y;
      mv.z += ov.z;
      mv.w += ov.w;
      *(float4*)(mp + j * 4) = mv;
      s1 += (mv.x + mv.y) + (mv.z + mv.w);
      s2 += (mv.x * mv.x + mv.y * mv.y) + (mv.z * mv.z + mv.w * mv.w);
    }
    s1 += __shfl_xor(s1, 1);
    s1 += __shfl_xor(s1, 2);
    s1 += __shfl_xor(s1, 4);
    s2 += __shfl_xor(s2, 1);
    s2 += __shfl_xor(s2, 2);
    s2 += __shfl_xor(s2, 4);
    if ((t & 7) == 0) {
      atomicAdd(s1p + b * SEQ + qglob, s1);
      atomicAdd(s2p + b * SEQ + qglob, s2);
    }
    __syncthreads();
  }
}

extern "C" void kernel_launch(void* const* d_in, const int* in_sizes, int n_in, void* d_out,
                              int out_size, void* d_ws, size_t ws_size, hipStream_t stream) {
  (void)in_sizes;
  (void)n_in;
  (void)out_size;
  (void)ws_size;
  const float* x = (const float*)d_in[0];
  const float* W_in = (const float*)d_in[1];
  const float* gamma = (const float*)d_in[2];
  const float* beta = (const float*)d_in[3];
  const float* Wq = (const float*)d_in[4];
  const float* Wk = (const float*)d_in[5];
  const float* Wv = (const float*)d_in[6];
  const float* Wf = (const float*)d_in[7];
  const float* bf = (const float*)d_in[8];
  float* out = (float*)d_out;

  char* ws = (char*)d_ws;
  const size_t MB = 1024ull * 1024;
  float* mod = (float*)ws;                 // 32 MB fp32 [8192,1024]
  u16* qb = (u16*)(ws + 32 * MB);          // 16 MB bf16 [B,H,S,E]
  u16* kb = (u16*)(ws + 48 * MB);          // 16 MB bf16 [B,H,S,E]
  u16* vtb = (u16*)(ws + 64 * MB);         // 16 MB bf16 [B,H,E,S]
  float* sums = (float*)(ws + 80 * MB);    // 4 x 32 KB: s1a,s2a,s1b,s2b
  float* s1a = sums;
  float* s2a = s1a + NROWS;
  float* s1b = s2a + NROWS;
  float* s2b = s1b + NROWS;
  u16* wqt = (u16*)(ws + 80 * MB + 4 * NROWS * sizeof(float));
  u16* wkt = wqt + NHEAD * ESPL * ESPL;
  u16* wvt = wkt + NHEAD * ESPL * ESPL;
  u16* wt2 = wvt + NHEAD * ESPL * ESPL;  // 2 MB Wf^T bf16
  u16* wt1 = (u16*)(ws + 32 * MB);       // W_in^T bf16 overlaps qb (dead before qkv writes qb)

  hipMemsetAsync(sums, 0, 4 * NROWS * sizeof(float), stream);
  wtrans_big<<<dim3(16, 16, 2), 256, 0, stream>>>(W_in, wt1, Wf, wt2);
  wtrans_small<<<dim3(2, 2, 24), 256, 0, stream>>>(Wq, Wk, Wv, wqt, wkt, wvt);

  dim3 gg(DIMN / 128, NROWS / 128);  // (8, 64)
  gemm_mfma<0><<<gg, 256, 0, stream>>>(x, wt1, nullptr, nullptr, nullptr, nullptr, s1a, s2a, mod);
  qkv_mfma<<<dim3(SEQ / 128, NB * NHEAD), 256, 0, stream>>>(mod, wqt, wkt, wvt, gamma, beta,
                                                            s1a, s2a, qb, kb, vtb);
  attn_mfma<<<dim3(SEQ / 128, NB * NHEAD), 256, 0, stream>>>(qb, kb, vtb, mod, s1b, s2b);
  gemm_mfma<1><<<gg, 256, 0, stream>>>(mod, wt2, mod, bf, gamma, beta, s1b, s2b, out);
}

// Round 7
// 314.986 us; speedup vs baseline: 1.3072x; 1.0834x over previous
//
#include <hip/hip_runtime.h>
#include <hip/hip_bf16.h>

#define DIMN 1024
#define NHEAD 8
#define ESPL 128
#define NB 4
#define SEQ 2048
#define NROWS (NB * SEQ)
#define LNEPS 1e-6f

typedef unsigned short u16;
typedef unsigned int u32;
typedef __attribute__((ext_vector_type(8))) short short8;
typedef __attribute__((ext_vector_type(4))) short s16x4;
typedef __attribute__((ext_vector_type(4))) float f32x4;

__device__ __forceinline__ u16 f2bf(float f) {
  u32 u = __float_as_uint(f);
  u += 0x7FFFu + ((u >> 16) & 1u);  // round-to-nearest-even
  return (u16)(u >> 16);
}

__device__ __forceinline__ uint2 pack4bf(float4 v) {
  uint2 r;
  r.x = (u32)f2bf(v.x) | ((u32)f2bf(v.y) << 16);
  r.y = (u32)f2bf(v.z) | ((u32)f2bf(v.w) << 16);
  return r;
}

__device__ __forceinline__ u32 pk2bf(float a, float b) {
  return (u32)f2bf(a) | ((u32)f2bf(b) << 16);
}

__device__ __forceinline__ float eluf(float x) { return x > 0.f ? x : expm1f(x); }

__device__ __forceinline__ float redsum16(float v) {
  v += __shfl_xor(v, 1);
  v += __shfl_xor(v, 2);
  v += __shfl_xor(v, 4);
  v += __shfl_xor(v, 8);
  return v;
}

// async global->LDS DMA, 16 B per lane; lds dest = wave-uniform base + lane*16
__device__ __forceinline__ void gl2lds16(const u16* g, u16* l) {
  __builtin_amdgcn_global_load_lds((const __attribute__((address_space(1))) u32*)g,
                                   (__attribute__((address_space(3))) u32*)l, 16, 0, 0);
}

// ------- fp32 -> bf16 flat convert (4 elems/thread) -------
__global__ __launch_bounds__(256) void conv_bf16(const float* __restrict__ src,
                                                 u16* __restrict__ dst) {
  int base = (blockIdx.x * 256 + threadIdx.x) * 4;
  *(uint2*)(dst + base) = pack4bf(*(const float4*)(src + base));
}

// ------- LN apply: modb = bf16(LN(mod)) using precomputed row sums -------
__global__ __launch_bounds__(256) void ln_apply(const float* __restrict__ modp,
                                                const float* __restrict__ gamma,
                                                const float* __restrict__ beta,
                                                const float* __restrict__ s1p,
                                                const float* __restrict__ s2p,
                                                u16* __restrict__ outb) {
  int base = (blockIdx.x * 256 + threadIdx.x) * 4;
  int row = base >> 10, col = base & 1023;
  float s1 = s1p[row], s2 = s2p[row];
  float mu = s1 * (1.f / DIMN);
  float rsd = rsqrtf(fmaxf(s2 * (1.f / DIMN) - mu * mu, 0.f) + LNEPS);
  float4 v = *(const float4*)(modp + base);
  float4 g = *(const float4*)(gamma + col);
  float4 bb = *(const float4*)(beta + col);
  v.x = (v.x - mu) * rsd * g.x + bb.x;
  v.y = (v.y - mu) * rsd * g.y + bb.y;
  v.z = (v.z - mu) * rsd * g.z + bb.z;
  v.w = (v.w - mu) * rsd * g.w + bb.w;
  *(uint2*)(outb + base) = pack4bf(v);
}

// ------- weight transpose + fp32->bf16: dst[n*K+k] = bf16(src[k*N+n]) -------
__device__ __forceinline__ void wtrans_body(const float* __restrict__ src,
                                            u16* __restrict__ dst, int K, int N, int n0,
                                            int k0) {
  __shared__ u16 tl[64][68];
  const int t = threadIdx.x;
  const int r = t >> 2;
#pragma unroll
  for (int j = 0; j < 4; j++) {
    int f = (t & 3) + j * 4;
    float4 v = *(const float4*)(src + (size_t)(k0 + r) * N + n0 + f * 4);
    *(uint2*)&tl[r][f * 4] = pack4bf(v);
  }
  __syncthreads();
#pragma unroll
  for (int j = 0; j < 4; j++) {
    int f = (t & 3) + j * 4;
    ushort4 o;
    o.x = tl[f * 4 + 0][r];
    o.y = tl[f * 4 + 1][r];
    o.z = tl[f * 4 + 2][r];
    o.w = tl[f * 4 + 3][r];
    *(ushort4*)(dst + (size_t)(n0 + r) * K + k0 + f * 4) = o;
  }
}

__global__ __launch_bounds__(256) void wtrans_big(const float* __restrict__ sA,
                                                  u16* __restrict__ dA,
                                                  const float* __restrict__ sB,
                                                  u16* __restrict__ dB) {
  const float* s = blockIdx.z ? sB : sA;
  u16* d = blockIdx.z ? dB : dA;
  wtrans_body(s, d, DIMN, DIMN, blockIdx.x * 64, blockIdx.y * 64);
}

__global__ __launch_bounds__(256) void wtrans_small(
    const float* __restrict__ sq, const float* __restrict__ sk, const float* __restrict__ sv,
    u16* __restrict__ dq, u16* __restrict__ dk, u16* __restrict__ dv) {
  const int mi = blockIdx.z >> 3, hh = blockIdx.z & 7;
  const float* s = (mi == 0) ? sq : (mi == 1) ? sk : sv;
  u16* d = (mi == 0) ? dq : (mi == 1) ? dk : dv;
  s += (size_t)hh * ESPL * ESPL;
  d += (size_t)hh * ESPL * ESPL;
  wtrans_body(s, d, ESPL, ESPL, blockIdx.x * 64, blockIdx.y * 64);
}

// ------- pure-bf16 MFMA GEMM: async-DMA double-buffered, 128x128 tile, BK=64 -------
// A bf16 [M x 1024] row-major; Bt bf16 [N x 1024] row-major (= B^T). XOR-swizzled
// unpadded tiles (16 KB each x 2 buffers). MODE 0: C fp32 + row sum/sumsq atomics.
// MODE 1: C = resid + elu(acc + bias).
template <int MODE>
__global__ __launch_bounds__(256, 2) void gemm_bf16(
    const u16* __restrict__ A, const u16* __restrict__ Bt, const float* __restrict__ resid,
    const float* __restrict__ bias, float* __restrict__ s1p, float* __restrict__ s2p,
    float* __restrict__ C) {
  __shared__ __align__(16) char lds[65536];  // [As0|Bs0|As1|Bs1] 16 KB each
  const int t = threadIdx.x;
  const int w = t >> 6, lane = t & 63, quad = lane >> 4, l16 = lane & 15;
  const int wm = w & 1, wn = w >> 1;
  const int m0 = blockIdx.y * 128, n0 = blockIdx.x * 128;

  auto stage = [&](int koff, int bi) {
    const u16* ag = A + (size_t)m0 * DIMN + koff;
    const u16* bg = Bt + (size_t)n0 * DIMN + koff;
    u16* As = (u16*)(lds + bi * 32768);
    u16* Bs = (u16*)(lds + bi * 32768 + 16384);
#pragma unroll
    for (int i = 0; i < 4; i++) {
      int pbase = (w * 4 + i) * 64;
      int p = pbase + lane;
      int r = p >> 3, c8 = (p & 7) ^ (r & 7);
      gl2lds16(ag + (size_t)r * DIMN + c8 * 8, As + pbase * 8);
      gl2lds16(bg + (size_t)r * DIMN + c8 * 8, Bs + pbase * 8);
    }
  };

  f32x4 acc[4][4];
#pragma unroll
  for (int mt = 0; mt < 4; mt++)
#pragma unroll
    for (int nt = 0; nt < 4; nt++) acc[mt][nt] = (f32x4){0.f, 0.f, 0.f, 0.f};

  stage(0, 0);
  __syncthreads();
  for (int kt = 0; kt < DIMN / 64; kt++) {
    if (kt + 1 < DIMN / 64) stage((kt + 1) * 64, (kt + 1) & 1);
    const u16* As = (const u16*)(lds + (kt & 1) * 32768);
    const u16* Bs = (const u16*)(lds + (kt & 1) * 32768 + 16384);
#pragma unroll
    for (int ks = 0; ks < 2; ks++) {
      short8 af[4], bfr[4];
#pragma unroll
      for (int mt = 0; mt < 4; mt++) {
        int row = wm * 64 + mt * 16 + l16;
        int pc = (ks * 4 + quad) ^ (row & 7);
        af[mt] = *(const short8*)(As + row * 64 + pc * 8);
      }
#pragma unroll
      for (int nt = 0; nt < 4; nt++) {
        int row = wn * 64 + nt * 16 + l16;
        int pc = (ks * 4 + quad) ^ (row & 7);
        bfr[nt] = *(const short8*)(Bs + row * 64 + pc * 8);
      }
#pragma unroll
      for (int mt = 0; mt < 4; mt++)
#pragma unroll
        for (int nt = 0; nt < 4; nt++)
          acc[mt][nt] = __builtin_amdgcn_mfma_f32_16x16x32_bf16(af[mt], bfr[nt], acc[mt][nt], 0, 0, 0);
    }
    __syncthreads();
  }
  // epilogue
#pragma unroll
  for (int mt = 0; mt < 4; mt++) {
#pragma unroll
    for (int r = 0; r < 4; r++) {
      int row = m0 + wm * 64 + mt * 16 + quad * 4 + r;
      float s1 = 0.f, s2 = 0.f;
#pragma unroll
      for (int nt = 0; nt < 4; nt++) {
        int col = n0 + wn * 64 + nt * 16 + l16;
        size_t off = (size_t)row * DIMN + col;
        float v = acc[mt][nt][r];
        if (MODE == 0) {
          C[off] = v;
          s1 += v;
          s2 += v * v;
        } else {
          C[off] = resid[off] + eluf(v + bias[col]);
        }
      }
      if (MODE == 0) {
        s1 = redsum16(s1);
        s2 = redsum16(s2);
        if (l16 == 0) {
          atomicAdd(s1p + row, s1);
          atomicAdd(s2p + row, s2);
        }
      }
    }
  }
}

// ------- QKV: per (b,h), 128 s-rows x 128 e, K=128; LN1 fused in A-staging -------
#define QP 136

__global__ __launch_bounds__(256) void qkv_mfma(
    const float* __restrict__ modp, const u16* __restrict__ wqt, const u16* __restrict__ wkt,
    const u16* __restrict__ wvt, const float* __restrict__ gamma, const float* __restrict__ beta,
    const float* __restrict__ s1p, const float* __restrict__ s2p, u16* __restrict__ qo,
    u16* __restrict__ ko, u16* __restrict__ vto) {
  __shared__ u16 Asl[128 * QP];
  __shared__ u16 Bsl[128 * QP];
  const int t = threadIdx.x;
  const int w = t >> 6, lane = t & 63, quad = lane >> 4, l16 = lane & 15;
  const int wm = w & 1, wn = w >> 1;
  const int s0 = blockIdx.x * 128;
  const int bh = blockIdx.y;
  const int b = bh >> 3, hh = bh & 7;
  const int sr8 = t >> 3, sf8 = t & 7;
#pragma unroll
  for (int p = 0; p < 4; p++) {
    int r = sr8 + 32 * p;
    int rowg = b * SEQ + s0 + r;
    float s1 = s1p[rowg], s2 = s2p[rowg];
    float mu = s1 * (1.f / DIMN);
    float rsd = rsqrtf(fmaxf(s2 * (1.f / DIMN) - mu * mu, 0.f) + LNEPS);
    const float* ap = modp + (size_t)rowg * DIMN + hh * ESPL;
#pragma unroll
    for (int j = 0; j < 4; j++) {
      int f = sf8 + j * 8;
      float4 v = *(const float4*)(ap + f * 4);
      float4 g = *(const float4*)(gamma + hh * ESPL + f * 4);
      float4 bb = *(const float4*)(beta + hh * ESPL + f * 4);
      v.x = (v.x - mu) * rsd * g.x + bb.x;
      v.y = (v.y - mu) * rsd * g.y + bb.y;
      v.z = (v.z - mu) * rsd * g.z + bb.z;
      v.w = (v.w - mu) * rsd * g.w + bb.w;
      *(uint2*)(Asl + r * QP + f * 4) = pack4bf(v);
    }
  }
  __syncthreads();
  short8 afr[4][4];
#pragma unroll
  for (int k4 = 0; k4 < 4; k4++)
#pragma unroll
    for (int mt = 0; mt < 4; mt++)
      afr[k4][mt] = *(const short8*)(Asl + (wm * 64 + mt * 16 + l16) * QP + k4 * 32 + quad * 8);

  const u16* Ws[3] = {wqt, wkt, wvt};
  for (int mi = 0; mi < 3; mi++) {
    __syncthreads();
    const u16* wsrc = Ws[mi] + ((size_t)hh << 14);
#pragma unroll
    for (int p = 0; p < 4; p++) {
      int r = sr8 + 32 * p;
#pragma unroll
      for (int j = 0; j < 2; j++) {
        int f = sf8 + j * 8;
        *(uint4*)(Bsl + r * QP + f * 8) = *(const uint4*)(wsrc + r * ESPL + f * 8);
      }
    }
    __syncthreads();
    f32x4 acc[4][4];
#pragma unroll
    for (int mt = 0; mt < 4; mt++)
#pragma unroll
      for (int nt = 0; nt < 4; nt++) acc[mt][nt] = (f32x4){0.f, 0.f, 0.f, 0.f};
#pragma unroll
    for (int k4 = 0; k4 < 4; k4++) {
      short8 bfr[4];
#pragma unroll
      for (int nt = 0; nt < 4; nt++)
        bfr[nt] = *(const short8*)(Bsl + (wn * 64 + nt * 16 + l16) * QP + k4 * 32 + quad * 8);
#pragma unroll
      for (int mt = 0; mt < 4; mt++)
#pragma unroll
        for (int nt = 0; nt < 4; nt++)
          acc[mt][nt] = __builtin_amdgcn_mfma_f32_16x16x32_bf16(afr[k4][mt], bfr[nt], acc[mt][nt], 0, 0, 0);
    }
    if (mi < 2) {
      u16* o = (mi == 0) ? qo : ko;
#pragma unroll
      for (int mt = 0; mt < 4; mt++)
#pragma unroll
        for (int r = 0; r < 4; r++) {
          int s = s0 + wm * 64 + mt * 16 + quad * 4 + r;
#pragma unroll
          for (int nt = 0; nt < 4; nt++) {
            int e = wn * 64 + nt * 16 + l16;
            o[((size_t)bh * SEQ + s) * ESPL + e] = f2bf(acc[mt][nt][r]);
          }
        }
    } else {
#pragma unroll
      for (int mt = 0; mt < 4; mt++)
#pragma unroll
        for (int nt = 0; nt < 4; nt++) {
          int e = wn * 64 + nt * 16 + l16;
          int sbase = s0 + wm * 64 + mt * 16 + quad * 4;
          ushort4 pk;
          pk.x = f2bf(acc[mt][nt][0]);
          pk.y = f2bf(acc[mt][nt][1]);
          pk.z = f2bf(acc[mt][nt][2]);
          pk.w = f2bf(acc[mt][nt][3]);
          *(ushort4*)(vto + ((size_t)bh * ESPL + e) * SEQ + sbase) = pk;
        }
    }
  }
}

// ------- MFMA flash attention v4: S^T formulation + async LDS double-buffer -------
#define OBP 132  // epilogue Obuf pitch (f32)

__global__ __launch_bounds__(256, 2) void attn_mfma(const u16* __restrict__ q,
                                                    const u16* __restrict__ kk,
                                                    const u16* __restrict__ vt,
                                                    float* __restrict__ modp,
                                                    float* __restrict__ s1p,
                                                    float* __restrict__ s2p) {
  __shared__ __align__(16) char lds[65536];  // [Ks0|Vs0|Ks1|Vs1] 16 KB each
  const int t = threadIdx.x;
  const int w = t >> 6, lane = t & 63, quad = lane >> 4, l16 = lane & 15;
  const int qt = blockIdx.x;  // 0..15
  const int bh = blockIdx.y;  // 0..31
  const int b = bh >> 3, hh = bh & 7;
  const size_t qkbase = (size_t)bh * SEQ * ESPL;
  const int qrow0 = qt * 128 + w * 32;
  const u16* kg0 = kk + qkbase;
  const u16* vg0 = vt + qkbase;

  short8 qf[2][4];
#pragma unroll
  for (int g = 0; g < 2; g++) {
    const u16* qrow = q + qkbase + (size_t)(qrow0 + g * 16 + l16) * ESPL + quad * 8;
#pragma unroll
    for (int kc = 0; kc < 4; kc++) qf[g][kc] = *(const short8*)(qrow + kc * 32);
  }

  float m_st[2] = {-1e30f, -1e30f}, l_st[2] = {0.f, 0.f};
  f32x4 oacc[2][8];
#pragma unroll
  for (int g = 0; g < 2; g++)
#pragma unroll
    for (int et = 0; et < 8; et++) oacc[g][et] = (f32x4){0.f, 0.f, 0.f, 0.f};

  auto stage = [&](int kt, int bi) {
    const u16* kg = kg0 + (size_t)kt * 64 * ESPL;
    const u16* vg = vg0 + (size_t)kt * 64;
    u16* Ksb = (u16*)(lds + bi * 32768);
    u16* Vsb = (u16*)(lds + bi * 32768 + 16384);
#pragma unroll
    for (int i = 0; i < 4; i++) {
      int pbase = w * 64 + i * 256;
      int p = pbase + lane;
      int r = p >> 4, c8 = (p & 15) ^ (r & 15);
      gl2lds16(kg + r * ESPL + c8 * 8, Ksb + pbase * 8);
      int e = p >> 3, v8 = (p & 7) ^ (e & 7);
      gl2lds16(vg + (size_t)e * SEQ + v8 * 8, Vsb + pbase * 8);
    }
  };

  stage(0, 0);
  __syncthreads();

  for (int kt = 0; kt < SEQ / 64; kt++) {
    if (kt + 1 < SEQ / 64) stage(kt + 1, (kt + 1) & 1);
    const u16* Ks = (const u16*)(lds + (kt & 1) * 32768);
    const u16* Vs = (const u16*)(lds + (kt & 1) * 32768 + 16384);
    f32x4 sacc[4][2];
#pragma unroll
    for (int mt = 0; mt < 4; mt++)
#pragma unroll
      for (int g = 0; g < 2; g++) sacc[mt][g] = (f32x4){0.f, 0.f, 0.f, 0.f};
#pragma unroll
    for (int mt = 0; mt < 4; mt++) {
#pragma unroll
      for (int kc = 0; kc < 4; kc++) {
        short8 kf = *(const short8*)(Ks + (mt * 16 + l16) * 128 + (((kc * 4 + quad) ^ l16) << 3));
        sacc[mt][0] = __builtin_amdgcn_mfma_f32_16x16x32_bf16(kf, qf[0][kc], sacc[mt][0], 0, 0, 0);
        sacc[mt][1] = __builtin_amdgcn_mfma_f32_16x16x32_bf16(kf, qf[1][kc], sacc[mt][1], 0, 0, 0);
      }
    }
    s16x4 pfrag[2][4];
    float alpha[2];
#pragma unroll
    for (int g = 0; g < 2; g++) {
      float mloc = sacc[0][g][0];
#pragma unroll
      for (int mt = 0; mt < 4; mt++)
#pragma unroll
        for (int r = 0; r < 4; r++) mloc = fmaxf(mloc, sacc[mt][g][r]);
      mloc = fmaxf(mloc, __shfl_xor(mloc, 16));
      mloc = fmaxf(mloc, __shfl_xor(mloc, 32));
      float mnew = fmaxf(m_st[g], mloc);
      alpha[g] = __expf(m_st[g] - mnew);
      m_st[g] = mnew;
      float sum = 0.f;
#pragma unroll
      for (int mt = 0; mt < 4; mt++) {
        float p0 = __expf(sacc[mt][g][0] - mnew);
        float p1 = __expf(sacc[mt][g][1] - mnew);
        float p2 = __expf(sacc[mt][g][2] - mnew);
        float p3 = __expf(sacc[mt][g][3] - mnew);
        sum += (p0 + p1) + (p2 + p3);
        union {
          s16x4 s;
          uint2 u;
        } cv;
        cv.u = make_uint2(pk2bf(p0, p1), pk2bf(p2, p3));
        pfrag[g][mt] = cv.s;
      }
      sum += __shfl_xor(sum, 16);
      sum += __shfl_xor(sum, 32);
      l_st[g] = l_st[g] * alpha[g] + sum;
    }
#pragma unroll
    for (int g = 0; g < 2; g++)
#pragma unroll
      for (int et = 0; et < 8; et++)
#pragma unroll
        for (int r = 0; r < 4; r++) oacc[g][et][r] *= alpha[g];
#pragma unroll
    for (int et = 0; et < 8; et++) {
#pragma unroll
      for (int mt = 0; mt < 4; mt++) {
        s16x4 vf = *(const s16x4*)(Vs + (size_t)(et * 16 + l16) * 64 +
                                   ((((mt * 2 + (quad >> 1)) ^ (l16 & 7)) << 3) + (quad & 1) * 4));
        oacc[0][et] = __builtin_amdgcn_mfma_f32_16x16x16bf16_1k(vf, pfrag[0][mt], oacc[0][et], 0, 0, 0);
        oacc[1][et] = __builtin_amdgcn_mfma_f32_16x16x16bf16_1k(vf, pfrag[1][mt], oacc[1][et], 0, 0, 0);
      }
    }
    __syncthreads();  // drains DMA + all waves done reading this buffer
  }

  float* Obuf = (float*)lds;
  const int rr = t >> 3, cc = (t & 7) << 4;
  for (int c = 0; c < 4; c++) {
    if (w == c) {
      float linv[2] = {1.f / l_st[0], 1.f / l_st[1]};
#pragma unroll
      for (int g = 0; g < 2; g++)
#pragma unroll
        for (int et = 0; et < 8; et++) {
          f32x4 ov = oacc[g][et];
          ov[0] *= linv[g];
          ov[1] *= linv[g];
          ov[2] *= linv[g];
          ov[3] *= linv[g];
          *(f32x4*)(Obuf + (size_t)(g * 16 + l16) * OBP + et * 16 + quad * 4) = ov;
        }
    }
    __syncthreads();
    int qglob = qt * 128 + c * 32 + rr;
    float* mp = modp + ((size_t)(b * SEQ + qglob)) * DIMN + hh * ESPL + cc;
    float s1 = 0.f, s2 = 0.f;
#pragma unroll
    for (int j = 0; j < 4; j++) {
      float4 ov = *(const float4*)(Obuf + (size_t)rr * OBP + cc + j * 4);
      float4 mv = *(const float4*)(mp + j * 4);
      mv.x += ov.x;
      mv.y += ov.y;
      mv.z += ov.z;
      mv.w += ov.w;
      *(float4*)(mp + j * 4) = mv;
      s1 += (mv.x + mv.y) + (mv.z + mv.w);
      s2 += (mv.x * mv.x + mv.y * mv.y) + (mv.z * mv.z + mv.w * mv.w);
    }
    s1 += __shfl_xor(s1, 1);
    s1 += __shfl_xor(s1, 2);
    s1 += __shfl_xor(s1, 4);
    s2 += __shfl_xor(s2, 1);
    s2 += __shfl_xor(s2, 2);
    s2 += __shfl_xor(s2, 4);
    if ((t & 7) == 0) {
      atomicAdd(s1p + b * SEQ + qglob, s1);
      atomicAdd(s2p + b * SEQ + qglob, s2);
    }
    __syncthreads();
  }
}

extern "C" void kernel_launch(void* const* d_in, const int* in_sizes, int n_in, void* d_out,
                              int out_size, void* d_ws, size_t ws_size, hipStream_t stream) {
  (void)in_sizes;
  (void)n_in;
  (void)out_size;
  (void)ws_size;
  const float* x = (const float*)d_in[0];
  const float* W_in = (const float*)d_in[1];
  const float* gamma = (const float*)d_in[2];
  const float* beta = (const float*)d_in[3];
  const float* Wq = (const float*)d_in[4];
  const float* Wk = (const float*)d_in[5];
  const float* Wv = (const float*)d_in[6];
  const float* Wf = (const float*)d_in[7];
  const float* bf = (const float*)d_in[8];
  float* out = (float*)d_out;

  char* ws = (char*)d_ws;
  const size_t MB = 1024ull * 1024;
  float* mod = (float*)ws;               // 32 MB fp32 [8192,1024]
  u16* qb = (u16*)(ws + 32 * MB);        // 16 MB bf16 [B,H,S,E]
  u16* kb = (u16*)(ws + 48 * MB);        // 16 MB bf16 [B,H,S,E]
  u16* vtb = (u16*)(ws + 64 * MB);       // 16 MB bf16 [B,H,E,S]
  float* sums = (float*)(ws + 80 * MB);  // 4 x 32 KB: s1a,s2a,s1b,s2b
  float* s1a = sums;
  float* s2a = s1a + NROWS;
  float* s1b = s2a + NROWS;
  float* s2b = s1b + NROWS;
  u16* wqt = (u16*)(ws + 80 * MB + 4 * NROWS * sizeof(float));
  u16* wkt = wqt + NHEAD * ESPL * ESPL;
  u16* wvt = wkt + NHEAD * ESPL * ESPL;
  u16* wt2 = wvt + NHEAD * ESPL * ESPL;  // 2 MB Wf^T bf16
  // overlays (lifetimes disjoint, stream-serial):
  u16* wt1 = qb;   // W_in^T bf16: wtrans -> gemm1; qb written by qkv after gemm1
  u16* xb = kb;    // x bf16: conv -> gemm1; kb written by qkv after gemm1
  u16* modb = qb;  // LN2(mod) bf16: ln_apply -> gemm2; qb dead after attn

  hipMemsetAsync(sums, 0, 4 * NROWS * sizeof(float), stream);
  conv_bf16<<<NROWS * DIMN / 1024, 256, 0, stream>>>(x, xb);
  wtrans_big<<<dim3(16, 16, 2), 256, 0, stream>>>(W_in, wt1, Wf, wt2);
  wtrans_small<<<dim3(2, 2, 24), 256, 0, stream>>>(Wq, Wk, Wv, wqt, wkt, wvt);

  dim3 gg(DIMN / 128, NROWS / 128);  // (8, 64)
  gemm_bf16<0><<<gg, 256, 0, stream>>>(xb, wt1, nullptr, nullptr, s1a, s2a, mod);
  qkv_mfma<<<dim3(SEQ / 128, NB * NHEAD), 256, 0, stream>>>(mod, wqt, wkt, wvt, gamma, beta,
                                                            s1a, s2a, qb, kb, vtb);
  attn_mfma<<<dim3(SEQ / 128, NB * NHEAD), 256, 0, stream>>>(qb, kb, vtb, mod, s1b, s2b);
  ln_apply<<<NROWS * DIMN / 1024, 256, 0, stream>>>(mod, gamma, beta, s1b, s2b, modb);
  gemm_bf16<1><<<gg, 256, 0, stream>>>(modb, wt2, mod, bf, nullptr, nullptr, out);
}